// Round 2
// baseline (430.085 us; speedup 1.0000x reference)
//
#include <hip/hip_runtime.h>

#define BIG 100000000.0f
constexpr int BATCH = 64;
constexpr int T = 512;     // N == M == 512
constexpr int DIMS = 64;

// ---------------------------------------------------------------------------
// Kernel A: pairwise squared distances D[b][n][m] = |x_n|^2 + |y_m|^2 - 2 x.y
// One block computes a 64x64 tile for one batch. 256 threads, 4x4 micro-tile.
// ---------------------------------------------------------------------------
__global__ __launch_bounds__(256) void pairdist_kernel(
    const float* __restrict__ x, const float* __restrict__ y,
    float* __restrict__ D) {
  int bid = blockIdx.x;
  int b = bid >> 6;          // / 64 tiles per batch
  int tile = bid & 63;
  int n0 = (tile >> 3) << 6; // row tile origin
  int m0 = (tile & 7) << 6;  // col tile origin

  __shared__ float xs[64][65];
  __shared__ float ys[64][65];
  __shared__ float x2s[64], y2s[64];

  const float* xb = x + ((size_t)b * T + n0) * DIMS;
  const float* yb = y + ((size_t)b * T + m0) * DIMS;
  int tid = threadIdx.x;

  for (int e = tid; e < 64 * 64; e += 256) {
    int r = e >> 6, c = e & 63;
    xs[r][c] = xb[(size_t)r * DIMS + c];
    ys[r][c] = yb[(size_t)r * DIMS + c];
  }
  __syncthreads();

  if (tid < 64) {
    float s = 0.f;
    #pragma unroll
    for (int k = 0; k < 64; ++k) { float v = xs[tid][k]; s += v * v; }
    x2s[tid] = s;
  } else if (tid < 128) {
    int r = tid - 64;
    float s = 0.f;
    #pragma unroll
    for (int k = 0; k < 64; ++k) { float v = ys[r][k]; s += v * v; }
    y2s[r] = s;
  }
  __syncthreads();

  int tr = tid >> 4, tc = tid & 15;
  int r0 = tr * 4, c0 = tc * 4;
  float acc[4][4] = {};
  #pragma unroll 8
  for (int k = 0; k < 64; ++k) {
    float a0 = xs[r0 + 0][k], a1 = xs[r0 + 1][k];
    float a2 = xs[r0 + 2][k], a3 = xs[r0 + 3][k];
    float b0 = ys[c0 + 0][k], b1 = ys[c0 + 1][k];
    float b2 = ys[c0 + 2][k], b3 = ys[c0 + 3][k];
    acc[0][0] += a0 * b0; acc[0][1] += a0 * b1; acc[0][2] += a0 * b2; acc[0][3] += a0 * b3;
    acc[1][0] += a1 * b0; acc[1][1] += a1 * b1; acc[1][2] += a1 * b2; acc[1][3] += a1 * b3;
    acc[2][0] += a2 * b0; acc[2][1] += a2 * b1; acc[2][2] += a2 * b2; acc[2][3] += a2 * b3;
    acc[3][0] += a3 * b0; acc[3][1] += a3 * b1; acc[3][2] += a3 * b2; acc[3][3] += a3 * b3;
  }

  #pragma unroll
  for (int r = 0; r < 4; ++r) {
    float4 v;
    float xn = x2s[r0 + r];
    v.x = xn + y2s[c0 + 0] - 2.f * acc[r][0];
    v.y = xn + y2s[c0 + 1] - 2.f * acc[r][1];
    v.z = xn + y2s[c0 + 2] - 2.f * acc[r][2];
    v.w = xn + y2s[c0 + 3] - 2.f * acc[r][3];
    *(float4*)&D[(((size_t)b * T) + (n0 + r0 + r)) * T + (m0 + c0)] = v;
  }
}

// ---------------------------------------------------------------------------
// Kernel B: anti-diagonal soft-DTW DP. One block per batch, 512 threads,
// thread tid owns row i = tid+1. 3 rotating diagonal buffers in LDS.
// Boundary fix: rc[0] (cell R[0, j]) must be re-set to BIG every diagonal,
// because the rotating buffer that held R[0,0]=0 cycles back as rp1/rp2.
// ---------------------------------------------------------------------------
__global__ __launch_bounds__(512) void dp_kernel(const float* __restrict__ D,
                                                 float* __restrict__ out) {
  int b = blockIdx.x;
  int tid = threadIdx.x;
  int i = tid + 1;

  __shared__ float rbuf[3][T + 1];
  for (int e = tid; e < 3 * (T + 1); e += 512) ((float*)rbuf)[e] = BIG;
  __syncthreads();
  if (tid == 0) rbuf[0][0] = 0.f;  // R[0,0]
  __syncthreads();

  // rotating pointers: rp2 = diag d-2, rp1 = diag d-1, rc = diag d
  float* rp2 = rbuf[0];
  float* rp1 = rbuf[1];
  float* rc  = rbuf[2];

  const float* Db = D + (size_t)b * T * T + (size_t)(i - 1) * T;  // my row

  // prefetch cost for d = 2
  float cost_next;
  {
    int j = 2 - i;
    int jj = min(max(j, 1), T) - 1;
    cost_next = Db[jj];
  }

  float val = BIG;
  for (int d = 2; d <= 2 * T; ++d) {
    float cost = cost_next;
    {
      int jn = d + 1 - i;
      int jjn = min(max(jn, 1), T) - 1;
      cost_next = Db[jjn];  // in flight across the barrier below
    }
    int j = d - i;
    float a = rp1[i - 1];   // R[i-1, j]
    float bb = rp1[i];      // R[i,   j-1]
    float c = rp2[i - 1];   // R[i-1, j-1]
    float m = fminf(fminf(a, bb), c);
    float s = __expf(m - a) + __expf(m - bb) + __expf(m - c);
    val = (j >= 1 && j <= T) ? (cost + m - __logf(s)) : BIG;
    rc[i] = val;
    if (tid == 0) rc[0] = BIG;  // R[0, d] = BIG — rc holds diag d-3, race-free
    __syncthreads();
    float* tmp = rp2; rp2 = rp1; rp1 = rc; rc = tmp;
  }

  if (tid == T - 1) atomicAdd(out, val * (1.0f / BATCH));
}

// ---------------------------------------------------------------------------
// Fallback (only if d_ws too small for the 64 MiB cost matrix):
// fused on-the-fly cost DP. y batch staged in padded LDS, x row in registers.
// ---------------------------------------------------------------------------
__global__ __launch_bounds__(512) void dp_onfly_kernel(
    const float* __restrict__ x, const float* __restrict__ y,
    float* __restrict__ out) {
  int b = blockIdx.x;
  int tid = threadIdx.x;
  int i = tid + 1;

  __shared__ float ys[T][DIMS + 1];   // padded
  __shared__ float y2s[T];
  __shared__ float rbuf[3][T + 1];

  const float* yb = y + (size_t)b * T * DIMS;
  for (int e = tid; e < T * DIMS; e += 512) {
    int r = e >> 6, c = e & 63;
    ys[r][c] = yb[e];
  }
  for (int e = tid; e < 3 * (T + 1); e += 512) ((float*)rbuf)[e] = BIG;
  __syncthreads();
  if (tid == 0) rbuf[0][0] = 0.f;
  {
    float s = 0.f;
    #pragma unroll
    for (int k = 0; k < DIMS; ++k) { float v = ys[tid][k]; s += v * v; }
    y2s[tid] = s;
  }

  float xr[DIMS];
  float x2 = 0.f;
  const float* xb = x + ((size_t)b * T + (i - 1)) * DIMS;
  #pragma unroll
  for (int k = 0; k < DIMS; ++k) { xr[k] = xb[k]; x2 += xr[k] * xr[k]; }
  __syncthreads();

  float* rp2 = rbuf[0];
  float* rp1 = rbuf[1];
  float* rc  = rbuf[2];

  float val = BIG;
  for (int d = 2; d <= 2 * T; ++d) {
    int j = d - i;
    bool valid = (j >= 1) && (j <= T);
    float cost = 0.f;
    if (valid) {
      float dot = 0.f;
      #pragma unroll
      for (int k = 0; k < DIMS; ++k) dot += xr[k] * ys[j - 1][k];
      cost = x2 + y2s[j - 1] - 2.f * dot;
    }
    float a = rp1[i - 1];
    float bb = rp1[i];
    float c = rp2[i - 1];
    float m = fminf(fminf(a, bb), c);
    float s = __expf(m - a) + __expf(m - bb) + __expf(m - c);
    val = valid ? (cost + m - __logf(s)) : BIG;
    rc[i] = val;
    if (tid == 0) rc[0] = BIG;  // boundary R[0, d] = BIG
    __syncthreads();
    float* tmp = rp2; rp2 = rp1; rp1 = rc; rc = tmp;
  }

  if (tid == T - 1) atomicAdd(out, val * (1.0f / BATCH));
}

extern "C" void kernel_launch(void* const* d_in, const int* in_sizes, int n_in,
                              void* d_out, int out_size, void* d_ws, size_t ws_size,
                              hipStream_t stream) {
  const float* x = (const float*)d_in[0];   // inputs  (B,T,D)
  const float* y = (const float*)d_in[1];   // targets (B,T,D)
  float* out = (float*)d_out;

  hipMemsetAsync(d_out, 0, sizeof(float), stream);

  size_t needD = (size_t)BATCH * T * T * sizeof(float);  // 64 MiB
  if (ws_size >= needD) {
    float* Dw = (float*)d_ws;
    pairdist_kernel<<<BATCH * 64, 256, 0, stream>>>(x, y, Dw);
    dp_kernel<<<BATCH, 512, 0, stream>>>(Dw, out);
  } else {
    dp_onfly_kernel<<<BATCH, 512, 0, stream>>>(x, y, out);
  }
}